// Round 8
// baseline (516.828 us; speedup 1.0000x reference)
//
#include <hip/hip_runtime.h>

#define N_NODES 50000
#define N_ENT   100000
#define N_REL   16
#define DIM     128
#define E_EDGES 600000
#define NQ      8192
#define PATH_DIM 5
#define NK      (N_NODES * N_REL)        /* 800000 (rel,dst) segments */
#define KTOT    (N_REL * DIM + DIM)      /* 2176 */
#define NG      (KTOT / 32)              /* 68 */
#define BM      64                       /* rows per block */
#define EB      ((E_EDGES + 255) / 256)  /* 2344 bucket blocks */
#define H0B     ((N_NODES * 32) / 256)   /* 6250 h0 blocks */
#define WCB     ((2 * NG * 8 * 512) / 256) /* 2176 wcat blocks */

typedef __attribute__((ext_vector_type(8))) short short8;
typedef __attribute__((ext_vector_type(4))) float floatx4;

static __device__ __forceinline__ short f2bf(float x) {
  unsigned u = __builtin_bit_cast(unsigned, x);
  u = (u + 0x7FFFu + ((u >> 16) & 1u)) >> 16;   // RNE
  return (short)u;
}
static __device__ __forceinline__ float bf_lo(unsigned u) {
  return __builtin_bit_cast(float, u << 16);
}
static __device__ __forceinline__ float bf_hi(unsigned u) {
  return __builtin_bit_cast(float, u & 0xffff0000u);
}
static __device__ __forceinline__ unsigned pk2(float a, float b) {
  return (unsigned)(unsigned short)f2bf(a) | ((unsigned)(unsigned short)f2bf(b) << 16);
}

// ---- manual VMEM: volatile asm loads, counted vmcnt (compiler can't sink/spill-order) ----
static __device__ __forceinline__ unsigned gload_u(const unsigned* p) {
  unsigned r;
  asm volatile("global_load_dword %0, %1, off" : "=v"(r) : "v"(p) : "memory");
  return r;
}
static __device__ __forceinline__ int gload_s(const int* p) {
  int r;
  asm volatile("global_load_dword %0, %1, off" : "=v"(r) : "v"(p) : "memory");
  return r;
}
static __device__ __forceinline__ short8 gload_b(const short* p) {
  short8 r;
  asm volatile("global_load_dwordx4 %0, %1, off" : "=v"(r) : "v"(p) : "memory");
  return r;
}
#define WAIT_VM(N) do { asm volatile("s_waitcnt vmcnt(" #N ")" ::: "memory"); \
                        __builtin_amdgcn_sched_barrier(0); } while (0)

// ---------- fused prep: edge bucketing | h0 gather | weight tiles (one launch) ----------
__global__ void k_prep(const int* __restrict__ ei, const int* __restrict__ et,
                       int* __restrict__ cnt, int* __restrict__ head,
                       int* __restrict__ cursor, int* __restrict__ slots,
                       int* __restrict__ ovf_src, int* __restrict__ ovf_next,
                       const int* __restrict__ nid, const float* __restrict__ emb,
                       unsigned* __restrict__ h,
                       const float* __restrict__ wrel, const float* __restrict__ wself,
                       short* __restrict__ wt) {
  int b = blockIdx.x, t = threadIdx.x;
  if (b < EB) {
    // capacity-4 direct buckets + overflow chain (order irrelevant for a sum)
    int e = b * 256 + t;
    if (e < E_EDGES) {
      int src = ei[e];
      int key = et[e] * N_NODES + ei[E_EDGES + e];
      int pos = atomicAdd(&cnt[key], 1);
      if (pos < 4) {
        slots[(size_t)key * 4 + pos] = src;
      } else {
        int nid2 = atomicAdd(cursor, 1) + 1;       // 1-based, 0 == null
        ovf_src[nid2] = src;
        ovf_next[nid2] = atomicExch(&head[key], nid2);
      }
    }
  } else if (b < EB + H0B) {
    int g = (b - EB) * 256 + t;                    // over N*32
    int n = g >> 5, q = g & 31;
    float4 v = *(const float4*)(emb + (size_t)nid[n] * DIM + q * 4);
    uint2 pk;
    pk.x = pk2(v.x, v.y);
    pk.y = pk2(v.z, v.w);
    *(uint2*)(h + (size_t)n * 64 + q * 2) = pk;
  } else {
    // wt layout: [l][g=k/32][nt8=n/16] tile [16 rA][32 q] shorts (1KB)
    int idx = (b - EB - H0B) * 256 + t;
    int within = idx & 511;
    int tile = idx >> 9;
    int rA = within >> 5, q = within & 31;
    int nt8 = tile & 7;
    int lg = tile >> 3;
    int l = lg / NG, g = lg % NG;
    int n = nt8 * 16 + rA;
    int k = g * 32 + q;
    float v;
    if (k < N_REL * DIM) {
      int r = k >> 7, d = k & 127;
      v = wrel[(((size_t)l * N_REL + r) * DIM + d) * DIM + n];
    } else {
      int d = k - N_REL * DIM;
      v = wself[((size_t)l * DIM + d) * DIM + n];
    }
    wt[idx] = f2bf(v);
  }
}

// ---------- fused layer: 8 merged waves, manual-vmcnt pipelined K-loop ----------
// Per iter: issue b(8) -> issue h(32)+cp(2) -> vmcnt(34) -> MFMA(prev) -> vmcnt(0)
// -> accumulate -> ds_write As -> barrier.  (b oldest, so vmcnt(34) = b done.)
__global__ __attribute__((amdgpu_flat_work_group_size(512, 512),
                          amdgpu_waves_per_eu(2, 4)))
void k_layer(const unsigned* __restrict__ hin, const int* __restrict__ gcnt,
             const int* __restrict__ slots, const int* __restrict__ head,
             const int* __restrict__ ovf_src, const int* __restrict__ ovf_next,
             const short* __restrict__ wt, const unsigned* __restrict__ zrow,
             unsigned* __restrict__ hout) {
  __shared__ unsigned As[2][BM][68];   // 272B row stride, double-buffered
  int t = threadIdx.x;
  int w = t >> 6, lane = t & 63;
  int quad = lane >> 4, rA = lane & 15;
  int wm = w >> 2, wn = w & 3;         // wave -> (row-half 32, col-quarter 32)
  int row0 = blockIdx.x * BM;
  int segbase = row0 + w * 8;          // this wave's 8 dst rows
  int lpi = lane & 31, segp = lpi & 7, edgep = lpi >> 3;

  floatx4 acc[2][2];
  #pragma unroll
  for (int a = 0; a < 2; a++)
    #pragma unroll
    for (int c = 0; c < 2; c++) acc[a][c] = (floatx4)0.f;

  unsigned u0[8], u1[8], u2[8], u3[8];
  short8 bf[4][2];
  int cl, pfe, cl_n, pfe_n;

  auto issue_batch = [&]() {           // 32 row loads, branchless (zrow fallback)
    #pragma unroll
    for (int j = 0; j < 8; ++j) {
      int cj = __builtin_amdgcn_readlane(cl, j);
      int r0 = __builtin_amdgcn_readlane(pfe, j);
      int r1 = __builtin_amdgcn_readlane(pfe, j + 8);
      int r2 = __builtin_amdgcn_readlane(pfe, j + 16);
      int r3 = __builtin_amdgcn_readlane(pfe, j + 24);
      u0[j] = gload_u(((cj > 0) ? hin + (size_t)r0 * 64 : zrow) + lane);
      u1[j] = gload_u(((cj > 1) ? hin + (size_t)r1 * 64 : zrow) + lane);
      u2[j] = gload_u(((cj > 2) ? hin + (size_t)r2 * 64 : zrow) + lane);
      u3[j] = gload_u(((cj > 3) ? hin + (size_t)r3 * 64 : zrow) + lane);
    }
  };
  auto issue_cp = [&](int itn) {       // next relation's cnt + 4 slot srcs
    int keyn = min(itn * N_NODES + segbase + segp, NK - 1);
    cl_n  = gload_s(gcnt + keyn);
    pfe_n = gload_s(slots + (size_t)keyn * 4 + edgep);
  };
  auto issue_b = [&](int rr) {         // 8 B-fragment loads (16B each)
    #pragma unroll
    for (int ks = 0; ks < 4; ++ks)
      #pragma unroll
      for (int ntl = 0; ntl < 2; ++ntl)
        bf[ks][ntl] = gload_b(wt + (size_t)((rr * 4 + ks) * 8 + wn * 2 + ntl) * 512
                                  + rA * 32 + quad * 8);
  };
  auto do_mfma = [&](int rr) {
    int buf = rr & 1;
    #pragma unroll
    for (int ks = 0; ks < 4; ++ks) {
      short8 a0 = *(const short8*)((const short*)&As[buf][wm * 32 + rA][0] + ks * 32 + quad * 8);
      short8 a1 = *(const short8*)((const short*)&As[buf][wm * 32 + 16 + rA][0] + ks * 32 + quad * 8);
      #pragma unroll
      for (int ntl = 0; ntl < 2; ++ntl) {
        acc[0][ntl] = __builtin_amdgcn_mfma_f32_16x16x32_bf16(a0, bf[ks][ntl], acc[0][ntl], 0, 0, 0);
        acc[1][ntl] = __builtin_amdgcn_mfma_f32_16x16x32_bf16(a1, bf[ks][ntl], acc[1][ntl], 0, 0, 0);
      }
    }
  };
  auto accum = [&](int it, int buf) {
    float invl = 1.0f / (float)(cl > 0 ? cl : 1);
    int invb = __builtin_bit_cast(int, invl);
    #pragma unroll
    for (int j = 0; j < 8; ++j) {
      int cj = __builtin_amdgcn_readlane(cl, j);
      float inv = __builtin_bit_cast(float, __builtin_amdgcn_readlane(invb, j));
      float s0 = bf_lo(u0[j]) + bf_lo(u1[j]) + bf_lo(u2[j]) + bf_lo(u3[j]);
      float s1 = bf_hi(u0[j]) + bf_hi(u1[j]) + bf_hi(u2[j]) + bf_hi(u3[j]);
      if (cj > 4) {                    // uniform, ~0.1% of segments: walk chain
        int kj = min(it * N_NODES + segbase + j, NK - 1);
        int cur = __builtin_amdgcn_readfirstlane(head[kj]);
        for (int x = 4; x < cj; ++x) {
          int sr = __builtin_amdgcn_readfirstlane(ovf_src[cur]);
          unsigned uu = hin[(size_t)sr * 64 + lane];
          s0 += bf_lo(uu); s1 += bf_hi(uu);
          cur = __builtin_amdgcn_readfirstlane(ovf_next[cur]);
        }
      }
      s0 *= inv; s1 *= inv;
      unsigned pk;
      asm("v_cvt_pk_bf16_f32 %0, %1, %2" : "=v"(pk) : "v"(s0), "v"(s1));  // RNE
      As[buf][w * 8 + j][lane] = pk;
    }
  };

  // ---- prologue: relation 0 (plain cnt/slot loads; compiler waits for them) ----
  {
    int key0 = min(segbase + segp, NK - 1);
    cl  = gcnt[key0];
    pfe = slots[(size_t)key0 * 4 + edgep];
  }
  issue_batch();                       // 32 outstanding
  issue_cp(1);                         // 34
  WAIT_VM(0);
  accum(0, 0);
  __syncthreads();
  cl = cl_n; pfe = pfe_n;

  // ---- main loop: relations 1..15 ----
  for (int it = 1; it <= 15; ++it) {
    issue_b(it - 1);                   // 8 (oldest)
    issue_batch();                     // 40
    issue_cp(it + 1);                  // 42 (it=15 -> clamped dummy, keeps counts uniform)
    WAIT_VM(34);                       // b done; h + cp still in flight
    do_mfma(it - 1);
    WAIT_VM(0);                        // h + cp done
    accum(it, it & 1);
    __syncthreads();
    cl = cl_n; pfe = pfe_n;
  }

  // ---- it = 16: self slot ----
  issue_b(15);                         // 8
  #pragma unroll
  for (int j = 0; j < 8; ++j)          // +8 = 16
    u0[j] = gload_u(hin + (size_t)min(segbase + j, N_NODES - 1) * 64 + lane);
  WAIT_VM(8);                          // b(15) done
  do_mfma(15);
  WAIT_VM(0);
  #pragma unroll
  for (int j = 0; j < 8; ++j) As[0][w * 8 + j][lane] = u0[j];
  __syncthreads();

  // ---- tail: MFMA(16) + epilogue ----
  issue_b(16);
  WAIT_VM(0);
  do_mfma(16);

  #pragma unroll
  for (int mt = 0; mt < 2; ++mt)
    #pragma unroll
    for (int ntl = 0; ntl < 2; ++ntl)
      #pragma unroll
      for (int j = 0; j < 4; ++j) {
        int row = row0 + wm * 32 + mt * 16 + quad * 4 + j;
        int col = wn * 32 + ntl * 16 + rA;
        if (row < N_NODES)
          ((short*)hout)[(size_t)row * DIM + col] = f2bf(fmaxf(acc[mt][ntl][j], 0.f));
      }
}

// ---------- scoring (bf16 h) ----------
__global__ void k_score(const unsigned* __restrict__ h, const int* __restrict__ heads,
                        const int* __restrict__ rels, const int* __restrict__ tails,
                        const float* __restrict__ rel_emb, const float* __restrict__ path_feat,
                        const int* __restrict__ task_idx, const float* __restrict__ delta_w,
                        const float* __restrict__ lambda_logit, const float* __restrict__ rule_init,
                        float* __restrict__ out) {
  int q = (blockIdx.x * 256 + threadIdx.x) >> 6;
  int lane = threadIdx.x & 63;
  int hd = heads[q], tl = tails[q], rl = rels[q];
  unsigned ua = h[(size_t)hd * 64 + lane];
  unsigned uc = h[(size_t)tl * 64 + lane];
  float2 r = *(const float2*)(rel_emb + (size_t)rl * DIM + lane * 2);
  float s = bf_lo(ua) * r.x * bf_lo(uc) + bf_hi(ua) * r.y * bf_hi(uc);
  #pragma unroll
  for (int off = 32; off; off >>= 1) s += __shfl_xor(s, off, 64);
  if (lane == 0) {
    int task = task_idx[0];
    float sp = 0.f;
    #pragma unroll
    for (int p = 0; p < PATH_DIM; p++)
      sp += path_feat[q * PATH_DIM + p] *
            (rule_init[task * PATH_DIM + p] + delta_w[task * PATH_DIM + p]);
    float lam = 1.f / (1.f + __expf(-lambda_logit[task]));
    out[q] = lam * s + (1.f - lam) * sp;
  }
}

extern "C" void kernel_launch(void* const* d_in, const int* in_sizes, int n_in,
                              void* d_out, int out_size, void* d_ws, size_t ws_size,
                              hipStream_t stream) {
  const int*   node_ids   = (const int*)d_in[0];
  const int*   edge_index = (const int*)d_in[1];
  const int*   edge_type  = (const int*)d_in[2];
  const int*   heads      = (const int*)d_in[3];
  const int*   rels       = (const int*)d_in[4];
  const int*   tails      = (const int*)d_in[5];
  const float* path_feat  = (const float*)d_in[6];
  const int*   task_idx   = (const int*)d_in[7];
  const float* entity_emb = (const float*)d_in[8];
  const float* rel_emb    = (const float*)d_in[9];
  const float* W_self     = (const float*)d_in[10];
  const float* W_rel      = (const float*)d_in[11];
  const float* delta_w    = (const float*)d_in[12];
  const float* lambda_lg  = (const float*)d_in[13];
  const float* rule_init  = (const float*)d_in[14];

  char* ws = (char*)d_ws;
  size_t off = 0;
  auto alloc = [&](size_t bytes) -> void* {
    void* p = ws + off;
    off = (off + bytes + 255) & ~(size_t)255;
    return p;
  };
  unsigned* h_a    = (unsigned*)alloc((size_t)N_NODES * DIM * 2);
  unsigned* h_b    = (unsigned*)alloc((size_t)N_NODES * DIM * 2);
  short*    wt     = (short*)alloc((size_t)2 * NG * 8 * 512 * 2);
  int*      zreg   = (int*)alloc((size_t)(2 * NK + 128) * 4);  // cnt | head | cursor | zrow
  int*      cntA   = zreg;
  int*      headA  = zreg + NK;
  int*      cursor = zreg + 2 * NK;
  unsigned* zrow   = (unsigned*)(zreg + 2 * NK + 64);
  int*      slots  = (int*)alloc((size_t)NK * 4 * 4);
  int*      ovf_s  = (int*)alloc((size_t)(E_EDGES + 2) * 4);
  int*      ovf_n  = (int*)alloc((size_t)(E_EDGES + 2) * 4);

  hipMemsetAsync(zreg, 0, (size_t)(2 * NK + 128) * 4, stream);
  k_prep<<<EB + H0B + WCB, 256, 0, stream>>>(edge_index, edge_type, cntA, headA,
                                             cursor, slots, ovf_s, ovf_n,
                                             node_ids, entity_emb, h_a,
                                             W_rel, W_self, wt);

  const unsigned* hin = h_a;
  unsigned* hout = h_b;
  int nblk = (N_NODES + BM - 1) / BM;
  for (int l = 0; l < 2; l++) {
    k_layer<<<nblk, 512, 0, stream>>>(hin, cntA, slots, headA, ovf_s, ovf_n,
                                      wt + (size_t)l * NG * 8 * 512, zrow, hout);
    const unsigned* tmp = hout;
    hout = (unsigned*)hin;
    hin = tmp;
  }
  k_score<<<NQ / 4, 256, 0, stream>>>(hin, heads, rels, tails, rel_emb, path_feat,
                                      task_idx, delta_w, lambda_lg, rule_init,
                                      (float*)d_out);
}

// Round 9
// 442.686 us; speedup vs baseline: 1.1675x; 1.1675x over previous
//
#include <hip/hip_runtime.h>

#define N_NODES 50000
#define N_ENT   100000
#define N_REL   16
#define DIM     128
#define E_EDGES 600000
#define NQ      8192
#define PATH_DIM 5
#define NK      (N_NODES * N_REL)        /* 800000 (rel,dst) segments, rel-major */
#define NBLK_SEG (NK / 256)              /* 3125 */
#define KTOT    (N_REL * DIM + DIM)      /* 2176 */
#define NG      (KTOT / 32)              /* 68 */
#define BM      64                       /* rows per block */
#define EB      ((E_EDGES + 255) / 256)  /* 2344 hist blocks */
#define H0B     ((N_NODES * 32) / 256)   /* 6250 h0 blocks */
#define WCB     ((2 * NG * 8 * 512) / 256) /* 2176 wcat blocks */

typedef __attribute__((ext_vector_type(8))) short short8;
typedef __attribute__((ext_vector_type(4))) float floatx4;

static __device__ __forceinline__ short f2bf(float x) {
  unsigned u = __builtin_bit_cast(unsigned, x);
  u = (u + 0x7FFFu + ((u >> 16) & 1u)) >> 16;   // RNE
  return (short)u;
}
static __device__ __forceinline__ float bf_lo(unsigned u) {
  return __builtin_bit_cast(float, u << 16);
}
static __device__ __forceinline__ float bf_hi(unsigned u) {
  return __builtin_bit_cast(float, u & 0xffff0000u);
}
static __device__ __forceinline__ unsigned pk2(float a, float b) {
  return (unsigned)(unsigned short)f2bf(a) | ((unsigned)(unsigned short)f2bf(b) << 16);
}

static __device__ __forceinline__ int wave_incl_scan(int x) {
  int lane = threadIdx.x & 63;
  #pragma unroll
  for (int off = 1; off < 64; off <<= 1) {
    int y = __shfl_up(x, off, 64);
    if (lane >= off) x += y;
  }
  return x;
}

// counted-vmcnt primitives: asm volatile pins program order; saddr form keeps
// address math scalar (SGPR base + shared VGPR byte offset).
static __device__ __forceinline__ unsigned gload_su(const unsigned* base, unsigned voff) {
  unsigned r;
  asm volatile("global_load_dword %0, %1, %2" : "=v"(r) : "v"(voff), "s"(base) : "memory");
  return r;
}
#define WAIT_VM(N) do { asm volatile("s_waitcnt vmcnt(" #N ")" ::: "memory"); \
                        __builtin_amdgcn_sched_barrier(0); } while (0)
// raw barrier: does NOT drain vmcnt (the round-8 lesson). LDS visibility via lgkmcnt.
#define BAR_LDS() do { asm volatile("s_waitcnt lgkmcnt(0)" ::: "memory"); \
                       __builtin_amdgcn_s_barrier(); \
                       asm volatile("" ::: "memory"); } while (0)

// ---------- fused prep: edge hist | h0 gather | weight tiles ----------
__global__ void k_prep(const int* __restrict__ ei, const int* __restrict__ et,
                       int* __restrict__ hist,
                       const int* __restrict__ nid, const float* __restrict__ emb,
                       unsigned* __restrict__ h,
                       const float* __restrict__ wrel, const float* __restrict__ wself,
                       short* __restrict__ wt) {
  int b = blockIdx.x, t = threadIdx.x;
  if (b < EB) {
    int e = b * 256 + t;
    if (e < E_EDGES) {
      int key = et[e] * N_NODES + ei[E_EDGES + e];
      atomicAdd(&hist[key], 1);
    }
  } else if (b < EB + H0B) {
    int g = (b - EB) * 256 + t;                    // over N*32
    int n = g >> 5, q = g & 31;
    float4 v = *(const float4*)(emb + (size_t)nid[n] * DIM + q * 4);
    uint2 pk;
    pk.x = pk2(v.x, v.y);
    pk.y = pk2(v.z, v.w);
    *(uint2*)(h + (size_t)n * 64 + q * 2) = pk;
  } else {
    // wt layout: [l][g=k/32][nt8=n/16] tile [16 rA][32 q] shorts (1KB)
    int idx = (b - EB - H0B) * 256 + t;
    int within = idx & 511;
    int tile = idx >> 9;
    int rA = within >> 5, q = within & 31;
    int nt8 = tile & 7;
    int lg = tile >> 3;
    int l = lg / NG, g = lg % NG;
    int n = nt8 * 16 + rA;
    int k = g * 32 + q;
    float v;
    if (k < N_REL * DIM) {
      int r = k >> 7, d = k & 127;
      v = wrel[(((size_t)l * N_REL + r) * DIM + d) * DIM + n];
    } else {
      int d = k - N_REL * DIM;
      v = wself[((size_t)l * DIM + d) * DIM + n];
    }
    wt[idx] = f2bf(v);
  }
}

__global__ void k_bsum(const int* __restrict__ hist, int* __restrict__ bsum) {
  int t = threadIdx.x;
  int v = hist[blockIdx.x * 256 + t];
  #pragma unroll
  for (int off = 32; off; off >>= 1) v += __shfl_xor(v, off, 64);
  __shared__ int s4[4];
  if ((t & 63) == 0) s4[t >> 6] = v;
  __syncthreads();
  if (t == 0) bsum[blockIdx.x] = s4[0] + s4[1] + s4[2] + s4[3];
}

__global__ void k_bscan(int* __restrict__ bsum) {   // 1 block, 1024 threads
  int t = threadIdx.x;
  int v[4], loc[4], s = 0;
  #pragma unroll
  for (int i = 0; i < 4; i++) {
    int idx = t * 4 + i;
    v[i] = (idx < NBLK_SEG) ? bsum[idx] : 0;
    loc[i] = s; s += v[i];
  }
  int incl = wave_incl_scan(s);
  __shared__ int wsum[16];
  int wid = t >> 6, lane = t & 63;
  if (lane == 63) wsum[wid] = incl;
  __syncthreads();
  if (t < 16) {
    int x = wsum[t];
    #pragma unroll
    for (int off = 1; off < 16; off <<= 1) {
      int y = __shfl_up(x, off, 64);
      if (t >= off) x += y;
    }
    wsum[t] = x;
  }
  __syncthreads();
  int wexcl = wid ? wsum[wid - 1] : 0;
  int texcl = wexcl + incl - s;
  #pragma unroll
  for (int i = 0; i < 4; i++) {
    int idx = t * 4 + i;
    if (idx < NBLK_SEG) bsum[idx] = texcl + loc[i];
  }
}

__global__ void k_offsets(const int* __restrict__ hist, const int* __restrict__ bsum,
                          int* __restrict__ offs, int* __restrict__ cursor) {
  int t = threadIdx.x;
  int g = blockIdx.x * 256 + t;
  int v = hist[g];
  int incl = wave_incl_scan(v);
  __shared__ int wsum[4];
  int wid = t >> 6, lane = t & 63;
  if (lane == 63) wsum[wid] = incl;
  __syncthreads();
  int wexcl = 0;
  for (int i = 0; i < wid; i++) wexcl += wsum[i];
  int off = bsum[blockIdx.x] + wexcl + incl - v;
  offs[g] = off;
  cursor[g] = off;
  if (g == NK - 1) offs[NK] = off + v;
}

__global__ void k_scatter(const int* __restrict__ ei, const int* __restrict__ et,
                          int* __restrict__ cursor, int* __restrict__ ssrc) {
  int e = blockIdx.x * 256 + threadIdx.x;
  if (e >= E_EDGES) return;
  int src = ei[e];
  int key = et[e] * N_NODES + ei[E_EDGES + e];
  int pos = atomicAdd(&cursor[key], 1);
  ssrc[pos] = src;
}

// ---------- fused layer: edge-compact producer pipeline + MFMA consumers ----------
// 4 producer waves (16 segs each) + 4 consumer waves. Raw s_barrier (no vmcnt
// drain) lets the 2-deep counted pipeline span phases:
//   entry: [sjvec(p+2)] + [u(p+1)]x32 = 33 outstanding
//   WAIT(32) -> sjvec(p+2) ready; issue sjvec(p+3), issue u(p+2)x32;
//   WAIT(33) -> u(p+1) ready; accum(rel p+1); lgkm(0); s_barrier.
__global__ __launch_bounds__(512, 4)
void k_layer(const unsigned* __restrict__ hin, const int* __restrict__ offs,
             const int* __restrict__ ssrc, const short* __restrict__ wt,
             unsigned* __restrict__ hout) {
  __shared__ unsigned As[2][BM][68];  // 272B row stride, double-buffered
  __shared__ int offsS[16][66];       // per-rel segment boundaries for block rows
  int t = threadIdx.x;
  int w = t >> 6, lane = t & 63;
  int row0 = blockIdx.x * BM;

  for (int idx = t; idx < 16 * 80; idx += 512) {
    int it = idx / 80, rr = idx - it * 80;
    if (rr < 65) offsS[it][rr] = offs[min(it * N_NODES + row0 + rr, NK)];
  }
  BAR_LDS();                          // barrier #0

  if (w < 4) {
    // ================= producer =================
    int w16 = w * 16;
    unsigned voffl = (unsigned)lane * 4u;   // shared per-lane byte offset
    unsigned uA[32], uB[32];
    int sjA, sjB;

    auto issue_sj = [&](int r) -> int {     // 64 edge ids of this wave's range
      int o0 = offsS[r][w16];
      unsigned vo = (unsigned)min(o0 + lane, E_EDGES - 1) * 4u;
      return (int)gload_su((const unsigned*)ssrc, vo);
    };
    auto issue_u = [&](unsigned (&u)[32], int sjv) {
      #pragma unroll
      for (int e = 0; e < 32; ++e) {
        int sr = __builtin_amdgcn_readlane(sjv, e);   // valid node id always
        u[e] = gload_su(hin + (size_t)sr * 64, voffl);
      }
    };
    auto accum = [&](unsigned (&u)[32], int r) {
      int olv = offsS[r][w16 + min(lane, 16)];
      int o0 = __builtin_amdgcn_readfirstlane(olv);
      int total = __builtin_amdgcn_readlane(olv, 16) - o0;
      int nxt = __shfl(olv, lane + 1);
      int cnl = nxt - olv;                            // lanes 0..15 meaningful
      float ivf = 1.0f / (float)(cnl > 0 ? cnl : 1);  // one div per wave-rel
      int ivb = __builtin_bit_cast(int, ivf);
      int k = 0;
      int nb = __builtin_amdgcn_readlane(olv, 1) - o0;
      float r0 = 0.f, r1 = 0.f;
      int buf = r & 1;
      auto close1 = [&]() {
        float f = __builtin_bit_cast(float, __builtin_amdgcn_readlane(ivb, k));
        float a = r0 * f, b2 = r1 * f;
        unsigned pk;
        asm("v_cvt_pk_bf16_f32 %0, %1, %2" : "=v"(pk) : "v"(a), "v"(b2));  // RNE
        As[buf][w16 + k][lane] = pk;
        r0 = 0.f; r1 = 0.f;
        ++k;
        nb = __builtin_amdgcn_readlane(olv, min(k + 1, 16)) - o0;
      };
      #pragma unroll
      for (int e = 0; e < 32; ++e) {
        while (k < 16 && nb == e) close1();           // segs ending at pos e (incl empties)
        if (e < total) { r0 += bf_lo(u[e]); r1 += bf_hi(u[e]); }
      }
      if (total > 32) {                               // rare serial tail (drains pipe; self-heals)
        for (int e = 32; e < total; ++e) {
          while (k < 16 && nb == e) close1();
          int sr = __builtin_amdgcn_readfirstlane(ssrc[o0 + e]);
          unsigned uu = hin[(size_t)sr * 64 + lane];
          r0 += bf_lo(uu); r1 += bf_hi(uu);
        }
      }
      while (k < 16) close1();                        // segs ending at total + trailing empties
    };

    // ---- prologue ----
    sjA = issue_sj(0);                 // [1]
    WAIT_VM(0);
    sjB = issue_sj(1);                 // [1]
    issue_u(uA, sjA);                  // [33]  rel 0
    WAIT_VM(32);                       // sjB ready; uA in flight
    sjA = issue_sj(2);                 // [33]
    issue_u(uB, sjB);                  // [65]  rel 1
    WAIT_VM(33);                       // uA ready
    accum(uA, 0);
    BAR_LDS();                         // barrier #1: As[0] visible

    // ---- phases p = 0..14 (produce rels 1..15) ----
    auto phase = [&](int p, unsigned (&uI)[32], unsigned (&uAcc)[32],
                     int &sjC, int &sjN) {
      WAIT_VM(32);                     // sjC (rel p+2) ready
      sjN = issue_sj(min(p + 3, 15));  // [33]
      issue_u(uI, sjC);                // [65]  rel p+2 (clamped loads harmless)
      WAIT_VM(33);                     // uAcc (rel p+1) ready
      accum(uAcc, p + 1);
      BAR_LDS();
    };
    for (int p = 0; p < 15; p += 2) {
      phase(p, uA, uB, sjA, sjB);
      if (p + 1 < 15) phase(p + 1, uB, uA, sjB, sjA);
    }

    // ---- self slot into As[0] (consumed at it=16) ----
    #pragma unroll
    for (int j = 0; j < 16; ++j) {
      int lr = min(row0 + w16 + j, N_NODES - 1);
      As[0][w16 + j][lane] = hin[(size_t)lr * 64 + lane];
    }
    BAR_LDS();                         // barrier #17
  } else {
    // ================= consumer =================
    int wid = w - 4, wm = wid >> 1, wn = wid & 1;
    int quad = lane >> 4, rA = lane & 15;
    floatx4 acc[2][4];
    #pragma unroll
    for (int a = 0; a < 2; a++)
      #pragma unroll
      for (int b = 0; b < 4; b++) acc[a][b] = (floatx4)0.f;

    BAR_LDS();                         // barrier #1 (matches producer prologue)
    for (int it = 0; it < 17; ++it) {
      int buf = it & 1;
      const short* arow0 = (const short*)&As[buf][wm * 32 + rA][0];
      const short* arow1 = (const short*)&As[buf][wm * 32 + 16 + rA][0];
      #pragma unroll
      for (int ks = 0; ks < 4; ++ks) {
        short8 a0 = *(const short8*)(arow0 + ks * 32 + quad * 8);
        short8 a1 = *(const short8*)(arow1 + ks * 32 + quad * 8);
        int kg = it * 4 + ks;
        const short* bp = wt + (size_t)(kg * 8 + wn * 4) * 512 + rA * 32 + quad * 8;
        #pragma unroll
        for (int nt = 0; nt < 4; ++nt) {
          short8 b = *(const short8*)(bp + nt * 512);  // 1KB tile, L2-hot
          acc[0][nt] = __builtin_amdgcn_mfma_f32_16x16x32_bf16(a0, b, acc[0][nt], 0, 0, 0);
          acc[1][nt] = __builtin_amdgcn_mfma_f32_16x16x32_bf16(a1, b, acc[1][nt], 0, 0, 0);
        }
      }
      if (it < 16) BAR_LDS();          // barriers #2..#17
    }
    // epilogue: C row=(lane>>4)*4+j, col=lane&15 within each 16x16 tile
    #pragma unroll
    for (int mt = 0; mt < 2; ++mt)
      #pragma unroll
      for (int nt = 0; nt < 4; ++nt)
        #pragma unroll
        for (int j = 0; j < 4; ++j) {
          int row = row0 + wm * 32 + mt * 16 + quad * 4 + j;
          int col = wn * 64 + nt * 16 + rA;
          if (row < N_NODES)
            ((short*)hout)[(size_t)row * DIM + col] = f2bf(fmaxf(acc[mt][nt][j], 0.f));
        }
  }
}

// ---------- scoring (bf16 h) ----------
__global__ void k_score(const unsigned* __restrict__ h, const int* __restrict__ heads,
                        const int* __restrict__ rels, const int* __restrict__ tails,
                        const float* __restrict__ rel_emb, const float* __restrict__ path_feat,
                        const int* __restrict__ task_idx, const float* __restrict__ delta_w,
                        const float* __restrict__ lambda_logit, const float* __restrict__ rule_init,
                        float* __restrict__ out) {
  int q = (blockIdx.x * 256 + threadIdx.x) >> 6;
  int lane = threadIdx.x & 63;
  int hd = heads[q], tl = tails[q], rl = rels[q];
  unsigned ua = h[(size_t)hd * 64 + lane];
  unsigned uc = h[(size_t)tl * 64 + lane];
  float2 r = *(const float2*)(rel_emb + (size_t)rl * DIM + lane * 2);
  float s = bf_lo(ua) * r.x * bf_lo(uc) + bf_hi(ua) * r.y * bf_hi(uc);
  #pragma unroll
  for (int off = 32; off; off >>= 1) s += __shfl_xor(s, off, 64);
  if (lane == 0) {
    int task = task_idx[0];
    float sp = 0.f;
    #pragma unroll
    for (int p = 0; p < PATH_DIM; p++)
      sp += path_feat[q * PATH_DIM + p] *
            (rule_init[task * PATH_DIM + p] + delta_w[task * PATH_DIM + p]);
    float lam = 1.f / (1.f + __expf(-lambda_logit[task]));
    out[q] = lam * s + (1.f - lam) * sp;
  }
}

extern "C" void kernel_launch(void* const* d_in, const int* in_sizes, int n_in,
                              void* d_out, int out_size, void* d_ws, size_t ws_size,
                              hipStream_t stream) {
  const int*   node_ids   = (const int*)d_in[0];
  const int*   edge_index = (const int*)d_in[1];
  const int*   edge_type  = (const int*)d_in[2];
  const int*   heads      = (const int*)d_in[3];
  const int*   rels       = (const int*)d_in[4];
  const int*   tails      = (const int*)d_in[5];
  const float* path_feat  = (const float*)d_in[6];
  const int*   task_idx   = (const int*)d_in[7];
  const float* entity_emb = (const float*)d_in[8];
  const float* rel_emb    = (const float*)d_in[9];
  const float* W_self     = (const float*)d_in[10];
  const float* W_rel      = (const float*)d_in[11];
  const float* delta_w    = (const float*)d_in[12];
  const float* lambda_lg  = (const float*)d_in[13];
  const float* rule_init  = (const float*)d_in[14];

  char* ws = (char*)d_ws;
  size_t off = 0;
  auto alloc = [&](size_t bytes) -> void* {
    void* p = ws + off;
    off = (off + bytes + 255) & ~(size_t)255;
    return p;
  };
  unsigned* h_a    = (unsigned*)alloc((size_t)N_NODES * DIM * 2);
  unsigned* h_b    = (unsigned*)alloc((size_t)N_NODES * DIM * 2);
  short*    wt     = (short*)alloc((size_t)2 * NG * 8 * 512 * 2);
  int*      offs   = (int*)alloc((size_t)(NK + 1) * 4);
  int*      ssrc   = (int*)alloc((size_t)E_EDGES * 4);
  int*      hist   = (int*)alloc((size_t)(NK + 1) * 4);
  int*      cursor = (int*)alloc((size_t)NK * 4);
  int*      bsum   = (int*)alloc((size_t)NBLK_SEG * 4);

  hipMemsetAsync(hist, 0, (size_t)(NK + 1) * 4, stream);
  k_prep<<<EB + H0B + WCB, 256, 0, stream>>>(edge_index, edge_type, hist,
                                             node_ids, entity_emb, h_a,
                                             W_rel, W_self, wt);
  k_bsum<<<NBLK_SEG, 256, 0, stream>>>(hist, bsum);
  k_bscan<<<1, 1024, 0, stream>>>(bsum);
  k_offsets<<<NBLK_SEG, 256, 0, stream>>>(hist, bsum, offs, cursor);
  k_scatter<<<EB, 256, 0, stream>>>(edge_index, edge_type, cursor, ssrc);

  const unsigned* hin = h_a;
  unsigned* hout = h_b;
  int nblk = (N_NODES + BM - 1) / BM;
  for (int l = 0; l < 2; l++) {
    k_layer<<<nblk, 512, 0, stream>>>(hin, offs, ssrc,
                                      wt + (size_t)l * NG * 8 * 512, hout);
    const unsigned* tmp = hout;
    hout = (unsigned*)hin;
    hin = tmp;
  }
  k_score<<<NQ / 4, 256, 0, stream>>>(hin, heads, rels, tails, rel_emb, path_feat,
                                      task_idx, delta_w, lambda_lg, rule_init,
                                      (float*)d_out);
}